// Round 1
// baseline (1382.767 us; speedup 1.0000x reference)
//
#include <hip/hip_runtime.h>
#include <stdint.h>

typedef unsigned long long ull;

#define NBATCH 8
#define NPTS   4096
#define NS     1024
#define NK     16
#define NF     64
#define NO     128

static __device__ __forceinline__ ull umax64(ull a, ull b) { return a > b ? a : b; }

// ---------------------------------------------------------------------------
// FPS: one block per batch, 256 threads, 16 points/thread (strided).
// Replicates numpy f32 semantics exactly: non-fused sub/mul/add, fminf,
// argmax with first-index tie-break (packed key, ~idx in low bits).
// Also writes sampled_pos output.
// ---------------------------------------------------------------------------
__global__ __launch_bounds__(256) void fps_kernel(const float* __restrict__ pos,
                                                  int* __restrict__ fps_idx,
                                                  float* __restrict__ out_pos) {
  const int b = blockIdx.x;
  const int t = threadIdx.x;
  __shared__ float plds[NPTS * 3];
  __shared__ ull wkeys[2][4];

  const float* p = pos + (size_t)b * NPTS * 3;
  for (int i = t; i < NPTS * 3; i += 256) plds[i] = p[i];
  __syncthreads();

  float px[16], py[16], pz[16], md[16];
#pragma unroll
  for (int j = 0; j < 16; ++j) {
    const int i = t + 256 * j;
    px[j] = plds[i * 3 + 0];
    py[j] = plds[i * 3 + 1];
    pz[j] = plds[i * 3 + 2];
    md[j] = 1e10f;
  }

  float lx = plds[0], ly = plds[1], lz = plds[2];
  if (t == 0) {
    fps_idx[b * NS] = 0;
    out_pos[(size_t)(b * NS) * 3 + 0] = lx;
    out_pos[(size_t)(b * NS) * 3 + 1] = ly;
    out_pos[(size_t)(b * NS) * 3 + 2] = lz;
  }

  for (int s = 1; s < NS; ++s) {
    ull best = 0;
#pragma unroll
    for (int j = 0; j < 16; ++j) {
      const float dx = __fsub_rn(px[j], lx);
      const float dy = __fsub_rn(py[j], ly);
      const float dz = __fsub_rn(pz[j], lz);
      const float d =
          __fadd_rn(__fadd_rn(__fmul_rn(dx, dx), __fmul_rn(dy, dy)), __fmul_rn(dz, dz));
      const float m = fminf(md[j], d);
      md[j] = m;
      const ull key =
          ((ull)__float_as_uint(m) << 32) | (unsigned)(4095 - (t + 256 * j));
      best = umax64(best, key);
    }
    // 64-lane butterfly reduce
#pragma unroll
    for (int off = 32; off >= 1; off >>= 1) {
      const ull o = __shfl_xor(best, off, 64);
      best = umax64(best, o);
    }
    if ((t & 63) == 0) wkeys[s & 1][t >> 6] = best;
    __syncthreads();
    const ull kk = umax64(umax64(wkeys[s & 1][0], wkeys[s & 1][1]),
                          umax64(wkeys[s & 1][2], wkeys[s & 1][3]));
    const int widx = 4095 - (int)(kk & 0xFFFFFFFFu);
    lx = plds[widx * 3 + 0];
    ly = plds[widx * 3 + 1];
    lz = plds[widx * 3 + 2];
    if (t == 0) {
      fps_idx[b * NS + s] = widx;
      out_pos[((size_t)b * NS + s) * 3 + 0] = lx;
      out_pos[((size_t)b * NS + s) * 3 + 1] = ly;
      out_pos[((size_t)b * NS + s) * 3 + 2] = lz;
    }
    // no second barrier: wkeys is double-buffered (slot s&1); the write to this
    // slot two steps later is fenced by the intervening step's barrier.
  }
}

// ---------------------------------------------------------------------------
// KNN: block = 32 samples x 8 chunks (256 threads), batch pos in LDS.
// Each thread keeps top-16 (packed u64 keys) of its 512-candidate chunk via
// replace-worst; chunk lists merged per-sample through LDS (reused buffer).
// ---------------------------------------------------------------------------
__global__ __launch_bounds__(256) void knn_kernel(const float* __restrict__ pos,
                                                  const int* __restrict__ fps_idx,
                                                  int* __restrict__ knn_idx) {
  __shared__ ull sbuf[NPTS * 3 / 2];  // 48KB, floats during scan, keys after
  float* plds = (float*)sbuf;
  const int b = blockIdx.y;
  const int t = threadIdx.x;

  const float* p = pos + (size_t)b * NPTS * 3;
  for (int i = t; i < NPTS * 3; i += 256) plds[i] = p[i];
  __syncthreads();

  const int samp = blockIdx.x * 32 + (t >> 3);
  const int chunk = t & 7;
  const int sidx = fps_idx[b * NS + samp];
  const float sx = plds[sidx * 3 + 0];
  const float sy = plds[sidx * 3 + 1];
  const float sz = plds[sidx * 3 + 2];

  ull keys[16];
#pragma unroll
  for (int k = 0; k < 16; ++k) keys[k] = 0xFFFFFFFF00000000ull | (unsigned)k;
  ull worst = 0xFFFFFFFF0000000Full;

  for (int j = 0; j < 512; ++j) {
    const int i = j * 8 + chunk;  // bank-conflict-free across chunks
    const float dx = plds[i * 3 + 0] - sx;
    const float dy = plds[i * 3 + 1] - sy;
    const float dz = plds[i * 3 + 2] - sz;
    const float d = dx * dx + dy * dy + dz * dz;
    const ull key = ((ull)__float_as_uint(d) << 32) | (unsigned)i;
    if (key < worst) {
#pragma unroll
      for (int k = 0; k < 16; ++k) keys[k] = (keys[k] == worst) ? key : keys[k];
      ull w = keys[0];
#pragma unroll
      for (int k = 1; k < 16; ++k) w = umax64(w, keys[k]);
      worst = w;
    }
  }
  __syncthreads();  // finished reading plds as floats
#pragma unroll
  for (int k = 0; k < 16; ++k) sbuf[t * 16 + k] = keys[k];
  __syncthreads();

  if (t < 32) {
    ull best[16];
#pragma unroll
    for (int k = 0; k < 16; ++k) best[k] = 0xFFFFFFFF00000000ull | (unsigned)(64 + k);
    ull w = 0xFFFFFFFF00000000ull | (unsigned)(64 + 15);
    for (int c = 0; c < 8; ++c) {
#pragma unroll
      for (int k = 0; k < 16; ++k) {
        const ull key = sbuf[(t * 8 + c) * 16 + k];
        if (key < w) {
#pragma unroll
          for (int q = 0; q < 16; ++q) best[q] = (best[q] == w) ? key : best[q];
          ull nw = best[0];
#pragma unroll
          for (int q = 1; q < 16; ++q) nw = umax64(nw, best[q]);
          w = nw;
        }
      }
    }
    const int sampg = blockIdx.x * 32 + t;
#pragma unroll
    for (int k = 0; k < 16; ++k)
      knn_idx[((size_t)b * NS + sampg) * NK + k] = (int)(best[k] & 0xFFFFFFFFu);
  }
}

// ---------------------------------------------------------------------------
// Stats: per-channel sum / sumsq of h = x W^T + b without materializing h.
// 256 blocks x 128 rows; thread = channel, W row in regs, x tile in LDS.
// ---------------------------------------------------------------------------
__global__ __launch_bounds__(128) void stats_kernel(const float* __restrict__ x,
                                                    const float* __restrict__ W,
                                                    const float* __restrict__ bias,
                                                    float* __restrict__ partial) {
  const int blk = blockIdx.x;
  const int c = threadIdx.x;
  __shared__ float xl[128 * 64];

  const float4* Wv = (const float4*)(W + c * NF);
  float4 w[16];
#pragma unroll
  for (int q = 0; q < 16; ++q) w[q] = Wv[q];
  const float bb = bias[c];

  const float4* src = (const float4*)(x + (size_t)blk * 128 * NF);
  float4* dst = (float4*)xl;
  for (int i = c; i < 128 * NF / 4; i += 128) dst[i] = src[i];
  __syncthreads();

  float s = 0.f, s2 = 0.f;
  for (int r = 0; r < 128; ++r) {
    const float4* xr = (const float4*)(xl + r * NF);
    float h = bb;
#pragma unroll
    for (int q = 0; q < 16; ++q) {
      const float4 xv = xr[q];
      h = fmaf(xv.x, w[q].x, h);
      h = fmaf(xv.y, w[q].y, h);
      h = fmaf(xv.z, w[q].z, h);
      h = fmaf(xv.w, w[q].w, h);
    }
    s += h;
    s2 = fmaf(h, h, s2);
  }
  partial[blk * 256 + c] = s;
  partial[blk * 256 + 128 + c] = s2;
}

__global__ __launch_bounds__(128) void stats_reduce_kernel(
    const float* __restrict__ partial, const float* __restrict__ gamma,
    const float* __restrict__ beta, float* __restrict__ ab) {
  const int c = threadIdx.x;
  double s = 0.0, s2 = 0.0;
  for (int blk = 0; blk < 256; ++blk) {
    s += (double)partial[blk * 256 + c];
    s2 += (double)partial[blk * 256 + 128 + c];
  }
  const double n = 32768.0;
  const double mean = s / n;
  const double var = s2 / n - mean * mean;
  const float inv = (float)(1.0 / sqrt(var + 1e-5));
  const float scale = gamma[c] * inv;
  const float shift = beta[c] - (float)mean * scale;
  ab[c] = scale;
  ab[128 + c] = shift;
}

// ---------------------------------------------------------------------------
// Gather-max: block = 8 samples of one batch, 128 threads (one per channel).
// Recomputes h for the 16 gathered rows (x rows staged in LDS, W row in regs),
// applies batchnorm (scale/shift) + relu, maxes over the 16 neighbors.
// ---------------------------------------------------------------------------
__global__ __launch_bounds__(128) void gather_kernel(const float* __restrict__ x,
                                                     const float* __restrict__ W,
                                                     const float* __restrict__ bias,
                                                     const float* __restrict__ ab,
                                                     const int* __restrict__ knn_idx,
                                                     float* __restrict__ out) {
  const int b = blockIdx.y;
  const int s0 = blockIdx.x * 8;
  const int c = threadIdx.x;

  const float4* Wv = (const float4*)(W + c * NF);
  float4 w[16];
#pragma unroll
  for (int q = 0; q < 16; ++q) w[q] = Wv[q];
  const float bb = bias[c];
  const float scale = ab[c];
  const float shift = ab[128 + c];

  __shared__ float xl[NK * NF];
  __shared__ int il[NK];
  const float* xb = x + (size_t)b * NPTS * NF;

  for (int ss = 0; ss < 8; ++ss) {
    const int samp = s0 + ss;
    if (c < NK) il[c] = knn_idx[((size_t)b * NS + samp) * NK + c];
    __syncthreads();
    {
      const int r = c >> 3;          // 0..15
      const int col = (c & 7) * 8;   // 0..56
      const float4* srow = (const float4*)(xb + (size_t)il[r] * NF + col);
      const float4 a0 = srow[0];
      const float4 a1 = srow[1];
      float4* drow = (float4*)(xl + r * NF + col);
      drow[0] = a0;
      drow[1] = a1;
    }
    __syncthreads();
    float m = 0.0f;  // relu outputs are >= 0, so 0 is a neutral init for max
#pragma unroll
    for (int k = 0; k < NK; ++k) {
      const float4* xr = (const float4*)(xl + k * NF);
      float h = bb;
#pragma unroll
      for (int q = 0; q < 16; ++q) {
        const float4 xv = xr[q];
        h = fmaf(xv.x, w[q].x, h);
        h = fmaf(xv.y, w[q].y, h);
        h = fmaf(xv.z, w[q].z, h);
        h = fmaf(xv.w, w[q].w, h);
      }
      h = fmaf(h, scale, shift);
      h = h > 0.f ? h : 0.f;
      m = m > h ? m : h;
    }
    out[((size_t)b * NS + samp) * NO + c] = m;
    __syncthreads();
  }
}

// ---------------------------------------------------------------------------
extern "C" void kernel_launch(void* const* d_in, const int* in_sizes, int n_in,
                              void* d_out, int out_size, void* d_ws, size_t ws_size,
                              hipStream_t stream) {
  const float* x     = (const float*)d_in[0];  // [8,4096,64]
  const float* pos   = (const float*)d_in[1];  // [8,4096,3]
  const float* W     = (const float*)d_in[2];  // [128,64]
  const float* bias  = (const float*)d_in[3];  // [128]
  const float* gamma = (const float*)d_in[4];  // [128]
  const float* beta  = (const float*)d_in[5];  // [128]
  // d_in[6] = n_sampling (=1024, hardcoded)

  float* out_knn = (float*)d_out;                       // [8,1024,128]
  float* out_pos = out_knn + (size_t)NBATCH * NS * NO;  // [8,1024,3]

  char* ws = (char*)d_ws;
  int* fps_idx  = (int*)(ws);                         // 8*1024 ints      (32KB)
  int* knn_idx  = (int*)(ws + (32 << 10));            // 8*1024*16 ints   (512KB)
  float* partial = (float*)(ws + (544 << 10));        // 256*256 floats   (256KB)
  float* ab      = (float*)(ws + (800 << 10));        // 256 floats

  fps_kernel<<<NBATCH, 256, 0, stream>>>(pos, fps_idx, out_pos);
  stats_kernel<<<256, 128, 0, stream>>>(x, W, bias, partial);
  stats_reduce_kernel<<<1, 128, 0, stream>>>(partial, gamma, beta, ab);
  knn_kernel<<<dim3(32, NBATCH), 256, 0, stream>>>(pos, fps_idx, knn_idx);
  gather_kernel<<<dim3(NS / 8, NBATCH), 128, 0, stream>>>(x, W, bias, ab, knn_idx,
                                                          out_knn);
}

// Round 2
// 1225.837 us; speedup vs baseline: 1.1280x; 1.1280x over previous
//
#include <hip/hip_runtime.h>
#include <stdint.h>

typedef unsigned long long ull;

#define NBATCH 8
#define NPTS   4096
#define NS     1024
#define NK     16
#define NF     64
#define NO     128

static __device__ __forceinline__ ull umax64(ull a, ull b) { return a > b ? a : b; }

// DPP max-reduce of a 64-bit key across the 64-lane wave; result in lane 63.
// Each level: shift/bcast lo+hi via DPP (VALU latency, ~5cy) + 64-bit max.
// bound_ctrl=true fills invalid lanes with 0, which never wins (keys > 0 for
// any real candidate that can be a max).
static __device__ __forceinline__ ull dpp_reduce_max_u64(ull v) {
#define DPP_STEP(ctrl)                                                        \
  {                                                                           \
    const unsigned lo = (unsigned)v;                                          \
    const unsigned hi = (unsigned)(v >> 32);                                  \
    const unsigned lo2 =                                                      \
        (unsigned)__builtin_amdgcn_update_dpp(0, (int)lo, ctrl, 0xf, 0xf, true); \
    const unsigned hi2 =                                                      \
        (unsigned)__builtin_amdgcn_update_dpp(0, (int)hi, ctrl, 0xf, 0xf, true); \
    const ull o = ((ull)hi2 << 32) | lo2;                                     \
    v = v > o ? v : o;                                                        \
  }
  DPP_STEP(0x111)  // row_shr:1
  DPP_STEP(0x112)  // row_shr:2
  DPP_STEP(0x114)  // row_shr:4
  DPP_STEP(0x118)  // row_shr:8  -> lane 15 of each row has row max
  DPP_STEP(0x142)  // row_bcast15 -> lane 31 has half max
  DPP_STEP(0x143)  // row_bcast31 -> lane 63 has wave max
#undef DPP_STEP
  return v;
}

// ---------------------------------------------------------------------------
// FPS: one block per batch, 256 threads, 16 points/thread (strided).
// Replicates numpy f32 semantics exactly: non-fused sub/mul/add, fminf,
// argmax with first-index tie-break (packed key, ~idx in low bits).
// Also writes sampled_pos output.
// ---------------------------------------------------------------------------
__global__ __launch_bounds__(256) void fps_kernel(const float* __restrict__ pos,
                                                  int* __restrict__ fps_idx,
                                                  float* __restrict__ out_pos) {
  const int b = blockIdx.x;
  const int t = threadIdx.x;
  __shared__ float plds[NPTS * 3];
  __shared__ ull wkeys[2][4];

  const float* p = pos + (size_t)b * NPTS * 3;
  for (int i = t; i < NPTS * 3; i += 256) plds[i] = p[i];
  __syncthreads();

  float px[16], py[16], pz[16], md[16];
#pragma unroll
  for (int j = 0; j < 16; ++j) {
    const int i = t + 256 * j;
    px[j] = plds[i * 3 + 0];
    py[j] = plds[i * 3 + 1];
    pz[j] = plds[i * 3 + 2];
    md[j] = 1e10f;
  }

  float lx = plds[0], ly = plds[1], lz = plds[2];
  if (t == 0) {
    fps_idx[b * NS] = 0;
    out_pos[(size_t)(b * NS) * 3 + 0] = lx;
    out_pos[(size_t)(b * NS) * 3 + 1] = ly;
    out_pos[(size_t)(b * NS) * 3 + 2] = lz;
  }

  for (int s = 1; s < NS; ++s) {
    ull best = 0;
#pragma unroll
    for (int j = 0; j < 16; ++j) {
      const float dx = __fsub_rn(px[j], lx);
      const float dy = __fsub_rn(py[j], ly);
      const float dz = __fsub_rn(pz[j], lz);
      const float d =
          __fadd_rn(__fadd_rn(__fmul_rn(dx, dx), __fmul_rn(dy, dy)), __fmul_rn(dz, dz));
      const float m = fminf(md[j], d);
      md[j] = m;
      const ull key =
          ((ull)__float_as_uint(m) << 32) | (unsigned)(4095 - (t + 256 * j));
      best = umax64(best, key);
    }
    // wave max via DPP (VALU-speed, no ds_swizzle latency); result in lane 63
    best = dpp_reduce_max_u64(best);
    if ((t & 63) == 63) wkeys[s & 1][t >> 6] = best;
    __syncthreads();
    const ull kk = umax64(umax64(wkeys[s & 1][0], wkeys[s & 1][1]),
                          umax64(wkeys[s & 1][2], wkeys[s & 1][3]));
    const int widx = 4095 - (int)(kk & 0xFFFFFFFFu);
    lx = plds[widx * 3 + 0];
    ly = plds[widx * 3 + 1];
    lz = plds[widx * 3 + 2];
    if (t == 0) {
      fps_idx[b * NS + s] = widx;
      out_pos[((size_t)b * NS + s) * 3 + 0] = lx;
      out_pos[((size_t)b * NS + s) * 3 + 1] = ly;
      out_pos[((size_t)b * NS + s) * 3 + 2] = lz;
    }
    // no second barrier: wkeys is double-buffered (slot s&1); the write to this
    // slot two steps later is fenced by the intervening step's barrier.
  }
}

// ---------------------------------------------------------------------------
// KNN: block = 32 samples x 8 chunks (256 threads), batch pos in LDS.
// Each thread keeps top-16 (packed u64 keys) of its 512-candidate chunk via
// replace-worst; chunk lists merged per-sample through LDS (reused buffer).
// ---------------------------------------------------------------------------
__global__ __launch_bounds__(256) void knn_kernel(const float* __restrict__ pos,
                                                  const int* __restrict__ fps_idx,
                                                  int* __restrict__ knn_idx) {
  __shared__ ull sbuf[NPTS * 3 / 2];  // 48KB, floats during scan, keys after
  float* plds = (float*)sbuf;
  const int b = blockIdx.y;
  const int t = threadIdx.x;

  const float* p = pos + (size_t)b * NPTS * 3;
  for (int i = t; i < NPTS * 3; i += 256) plds[i] = p[i];
  __syncthreads();

  const int samp = blockIdx.x * 32 + (t >> 3);
  const int chunk = t & 7;
  const int sidx = fps_idx[b * NS + samp];
  const float sx = plds[sidx * 3 + 0];
  const float sy = plds[sidx * 3 + 1];
  const float sz = plds[sidx * 3 + 2];

  ull keys[16];
#pragma unroll
  for (int k = 0; k < 16; ++k) keys[k] = 0xFFFFFFFF00000000ull | (unsigned)k;
  ull worst = 0xFFFFFFFF0000000Full;

  for (int j = 0; j < 512; ++j) {
    const int i = j * 8 + chunk;  // bank-conflict-free across chunks
    const float dx = plds[i * 3 + 0] - sx;
    const float dy = plds[i * 3 + 1] - sy;
    const float dz = plds[i * 3 + 2] - sz;
    const float d = dx * dx + dy * dy + dz * dz;
    const ull key = ((ull)__float_as_uint(d) << 32) | (unsigned)i;
    if (key < worst) {
#pragma unroll
      for (int k = 0; k < 16; ++k) keys[k] = (keys[k] == worst) ? key : keys[k];
      ull w = keys[0];
#pragma unroll
      for (int k = 1; k < 16; ++k) w = umax64(w, keys[k]);
      worst = w;
    }
  }
  __syncthreads();  // finished reading plds as floats
#pragma unroll
  for (int k = 0; k < 16; ++k) sbuf[t * 16 + k] = keys[k];
  __syncthreads();

  if (t < 32) {
    ull best[16];
#pragma unroll
    for (int k = 0; k < 16; ++k) best[k] = 0xFFFFFFFF00000000ull | (unsigned)(64 + k);
    ull w = 0xFFFFFFFF00000000ull | (unsigned)(64 + 15);
    for (int c = 0; c < 8; ++c) {
#pragma unroll
      for (int k = 0; k < 16; ++k) {
        const ull key = sbuf[(t * 8 + c) * 16 + k];
        if (key < w) {
#pragma unroll
          for (int q = 0; q < 16; ++q) best[q] = (best[q] == w) ? key : best[q];
          ull nw = best[0];
#pragma unroll
          for (int q = 1; q < 16; ++q) nw = umax64(nw, best[q]);
          w = nw;
        }
      }
    }
    const int sampg = blockIdx.x * 32 + t;
#pragma unroll
    for (int k = 0; k < 16; ++k)
      knn_idx[((size_t)b * NS + sampg) * NK + k] = (int)(best[k] & 0xFFFFFFFFu);
  }
}

// ---------------------------------------------------------------------------
// Stats: per-channel sum / sumsq of h = x W^T + b without materializing h.
// 256 blocks x 128 rows; thread = channel, W row in regs, x tile in LDS.
// ---------------------------------------------------------------------------
__global__ __launch_bounds__(128) void stats_kernel(const float* __restrict__ x,
                                                    const float* __restrict__ W,
                                                    const float* __restrict__ bias,
                                                    float* __restrict__ partial) {
  const int blk = blockIdx.x;
  const int c = threadIdx.x;
  __shared__ float xl[128 * 64];

  const float4* Wv = (const float4*)(W + c * NF);
  float4 w[16];
#pragma unroll
  for (int q = 0; q < 16; ++q) w[q] = Wv[q];
  const float bb = bias[c];

  const float4* src = (const float4*)(x + (size_t)blk * 128 * NF);
  float4* dst = (float4*)xl;
  for (int i = c; i < 128 * NF / 4; i += 128) dst[i] = src[i];
  __syncthreads();

  float s = 0.f, s2 = 0.f;
  for (int r = 0; r < 128; ++r) {
    const float4* xr = (const float4*)(xl + r * NF);
    float h = bb;
#pragma unroll
    for (int q = 0; q < 16; ++q) {
      const float4 xv = xr[q];
      h = fmaf(xv.x, w[q].x, h);
      h = fmaf(xv.y, w[q].y, h);
      h = fmaf(xv.z, w[q].z, h);
      h = fmaf(xv.w, w[q].w, h);
    }
    s += h;
    s2 = fmaf(h, h, s2);
  }
  partial[blk * 256 + c] = s;
  partial[blk * 256 + 128 + c] = s2;
}

// 256 threads: thread (c, half) sums 128 of 256 block-partials; LDS combine.
__global__ __launch_bounds__(256) void stats_reduce_kernel(
    const float* __restrict__ partial, const float* __restrict__ gamma,
    const float* __restrict__ beta, float* __restrict__ ab) {
  const int t = threadIdx.x;
  const int c = t & 127;
  const int h = t >> 7;
  __shared__ double sred[256], s2red[256];
  double s = 0.0, s2 = 0.0;
#pragma unroll 4
  for (int blk = h * 128; blk < h * 128 + 128; ++blk) {
    s += (double)partial[blk * 256 + c];
    s2 += (double)partial[blk * 256 + 128 + c];
  }
  sred[t] = s;
  s2red[t] = s2;
  __syncthreads();
  if (t < 128) {
    s = sred[t] + sred[t + 128];
    s2 = s2red[t] + s2red[t + 128];
    const double n = 32768.0;
    const double mean = s / n;
    const double var = s2 / n - mean * mean;
    const float inv = (float)(1.0 / sqrt(var + 1e-5));
    const float scale = gamma[t] * inv;
    const float shift = beta[t] - (float)mean * scale;
    ab[t] = scale;
    ab[128 + t] = shift;
  }
}

// ---------------------------------------------------------------------------
// Gather-max: block = 8 samples of one batch, 128 threads (one per channel).
// Recomputes h for the 16 gathered rows (x rows staged in LDS, W row in regs),
// applies batchnorm (scale/shift) + relu, maxes over the 16 neighbors.
// ---------------------------------------------------------------------------
__global__ __launch_bounds__(128) void gather_kernel(const float* __restrict__ x,
                                                     const float* __restrict__ W,
                                                     const float* __restrict__ bias,
                                                     const float* __restrict__ ab,
                                                     const int* __restrict__ knn_idx,
                                                     float* __restrict__ out) {
  const int b = blockIdx.y;
  const int s0 = blockIdx.x * 8;
  const int c = threadIdx.x;

  const float4* Wv = (const float4*)(W + c * NF);
  float4 w[16];
#pragma unroll
  for (int q = 0; q < 16; ++q) w[q] = Wv[q];
  const float bb = bias[c];
  const float scale = ab[c];
  const float shift = ab[128 + c];

  __shared__ float xl[NK * NF];
  __shared__ int il[NK];
  const float* xb = x + (size_t)b * NPTS * NF;

  for (int ss = 0; ss < 8; ++ss) {
    const int samp = s0 + ss;
    if (c < NK) il[c] = knn_idx[((size_t)b * NS + samp) * NK + c];
    __syncthreads();
    {
      const int r = c >> 3;          // 0..15
      const int col = (c & 7) * 8;   // 0..56
      const float4* srow = (const float4*)(xb + (size_t)il[r] * NF + col);
      const float4 a0 = srow[0];
      const float4 a1 = srow[1];
      float4* drow = (float4*)(xl + r * NF + col);
      drow[0] = a0;
      drow[1] = a1;
    }
    __syncthreads();
    float m = 0.0f;  // relu outputs are >= 0, so 0 is a neutral init for max
#pragma unroll
    for (int k = 0; k < NK; ++k) {
      const float4* xr = (const float4*)(xl + k * NF);
      float h = bb;
#pragma unroll
      for (int q = 0; q < 16; ++q) {
        const float4 xv = xr[q];
        h = fmaf(xv.x, w[q].x, h);
        h = fmaf(xv.y, w[q].y, h);
        h = fmaf(xv.z, w[q].z, h);
        h = fmaf(xv.w, w[q].w, h);
      }
      h = fmaf(h, scale, shift);
      h = h > 0.f ? h : 0.f;
      m = m > h ? m : h;
    }
    out[((size_t)b * NS + samp) * NO + c] = m;
    __syncthreads();
  }
}

// ---------------------------------------------------------------------------
extern "C" void kernel_launch(void* const* d_in, const int* in_sizes, int n_in,
                              void* d_out, int out_size, void* d_ws, size_t ws_size,
                              hipStream_t stream) {
  const float* x     = (const float*)d_in[0];  // [8,4096,64]
  const float* pos   = (const float*)d_in[1];  // [8,4096,3]
  const float* W     = (const float*)d_in[2];  // [128,64]
  const float* bias  = (const float*)d_in[3];  // [128]
  const float* gamma = (const float*)d_in[4];  // [128]
  const float* beta  = (const float*)d_in[5];  // [128]
  // d_in[6] = n_sampling (=1024, hardcoded)

  float* out_knn = (float*)d_out;                       // [8,1024,128]
  float* out_pos = out_knn + (size_t)NBATCH * NS * NO;  // [8,1024,3]

  char* ws = (char*)d_ws;
  int* fps_idx  = (int*)(ws);                         // 8*1024 ints      (32KB)
  int* knn_idx  = (int*)(ws + (32 << 10));            // 8*1024*16 ints   (512KB)
  float* partial = (float*)(ws + (544 << 10));        // 256*256 floats   (256KB)
  float* ab      = (float*)(ws + (800 << 10));        // 256 floats

  fps_kernel<<<NBATCH, 256, 0, stream>>>(pos, fps_idx, out_pos);
  stats_kernel<<<256, 128, 0, stream>>>(x, W, bias, partial);
  stats_reduce_kernel<<<1, 256, 0, stream>>>(partial, gamma, beta, ab);
  knn_kernel<<<dim3(32, NBATCH), 256, 0, stream>>>(pos, fps_idx, knn_idx);
  gather_kernel<<<dim3(NS / 8, NBATCH), 128, 0, stream>>>(x, W, bias, ab, knn_idx,
                                                          out_knn);
}

// Round 3
// 1174.555 us; speedup vs baseline: 1.1773x; 1.0437x over previous
//
#include <hip/hip_runtime.h>
#include <stdint.h>

typedef unsigned long long ull;
typedef float f32x2 __attribute__((ext_vector_type(2)));

#define NBATCH 8
#define NPTS   4096
#define NS     1024
#define NK     16
#define NF     64
#define NO     128

#define FT  512  // fps threads
#define PPT 8    // points per thread (4096/512)

static __device__ __forceinline__ ull umax64(ull a, ull b) { return a > b ? a : b; }

// DPP max-reduce of a 64-bit key across the 64-lane wave; result in lane 63.
static __device__ __forceinline__ ull dpp_reduce_max_u64(ull v) {
#define DPP_STEP(ctrl)                                                        \
  {                                                                           \
    const unsigned lo = (unsigned)v;                                          \
    const unsigned hi = (unsigned)(v >> 32);                                  \
    const unsigned lo2 =                                                      \
        (unsigned)__builtin_amdgcn_update_dpp(0, (int)lo, ctrl, 0xf, 0xf, true); \
    const unsigned hi2 =                                                      \
        (unsigned)__builtin_amdgcn_update_dpp(0, (int)hi, ctrl, 0xf, 0xf, true); \
    const ull o = ((ull)hi2 << 32) | lo2;                                     \
    v = v > o ? v : o;                                                        \
  }
  DPP_STEP(0x111)  // row_shr:1
  DPP_STEP(0x112)  // row_shr:2
  DPP_STEP(0x114)  // row_shr:4
  DPP_STEP(0x118)  // row_shr:8
  DPP_STEP(0x142)  // row_bcast15
  DPP_STEP(0x143)  // row_bcast31 -> lane 63 has wave max
#undef DPP_STEP
  return v;
}

// ---------------------------------------------------------------------------
// FPS: one block per batch, 512 threads (8 waves, 2/SIMD for latency overlap),
// 8 points/thread. Packed-f32 (v_pk_*) distance math, bit-exact vs numpy
// (contract off; pk ops are IEEE f32). Cross-wave argmax via LDS atomicMax
// on a 4-slot rotating buffer (reset 2 epochs ahead; disjoint slots per epoch).
// ---------------------------------------------------------------------------
__global__ __launch_bounds__(FT) void fps_kernel(const float* __restrict__ pos,
                                                 int* __restrict__ fps_idx,
                                                 float* __restrict__ out_pos) {
#pragma clang fp contract(off)
  const int b = blockIdx.x;
  const int t = threadIdx.x;
  __shared__ float plds[NPTS * 3];
  __shared__ ull slot[4];

  const float* p = pos + (size_t)b * NPTS * 3;
  {
    const float4* src = (const float4*)p;
    float4* dst = (float4*)plds;
    for (int i = t; i < NPTS * 3 / 4; i += FT) dst[i] = src[i];
  }
  if (t < 4) slot[t] = 0;
  __syncthreads();

  f32x2 px2[PPT / 2], py2[PPT / 2], pz2[PPT / 2], md2[PPT / 2];
  unsigned lowk[PPT];
#pragma unroll
  for (int jp = 0; jp < PPT / 2; ++jp) {
    const int i0 = t + FT * (2 * jp);
    const int i1 = i0 + FT;
    px2[jp] = (f32x2){plds[3 * i0 + 0], plds[3 * i1 + 0]};
    py2[jp] = (f32x2){plds[3 * i0 + 1], plds[3 * i1 + 1]};
    pz2[jp] = (f32x2){plds[3 * i0 + 2], plds[3 * i1 + 2]};
    md2[jp] = (f32x2){1e10f, 1e10f};
    lowk[2 * jp] = 4095 - i0;
    lowk[2 * jp + 1] = 4095 - i1;
  }

  float lx = plds[0], ly = plds[1], lz = plds[2];
  if (t == 0) {
    fps_idx[b * NS] = 0;
    out_pos[(size_t)(b * NS) * 3 + 0] = lx;
    out_pos[(size_t)(b * NS) * 3 + 1] = ly;
    out_pos[(size_t)(b * NS) * 3 + 2] = lz;
  }

#pragma unroll 4
  for (int s = 1; s < NS; ++s) {
    const f32x2 lxv = (f32x2){lx, lx};
    const f32x2 lyv = (f32x2){ly, ly};
    const f32x2 lzv = (f32x2){lz, lz};
    ull best = 0;
#pragma unroll
    for (int jp = 0; jp < PPT / 2; ++jp) {
      const f32x2 dx = px2[jp] - lxv;        // v_pk_add (neg) — IEEE f32
      const f32x2 dy = py2[jp] - lyv;
      const f32x2 dz = pz2[jp] - lzv;
      const f32x2 xx = dx * dx;              // v_pk_mul
      const f32x2 yy = dy * dy;
      const f32x2 zz = dz * dz;
      const f32x2 sxy = xx + yy;             // v_pk_add
      const f32x2 d = sxy + zz;              // ((dx^2+dy^2)+dz^2), numpy order
      const float m0 = fminf(md2[jp].x, d.x);
      const float m1 = fminf(md2[jp].y, d.y);
      md2[jp].x = m0;
      md2[jp].y = m1;
      const ull k0 = ((ull)__float_as_uint(m0) << 32) | lowk[2 * jp];
      const ull k1 = ((ull)__float_as_uint(m1) << 32) | lowk[2 * jp + 1];
      best = umax64(best, umax64(k0, k1));
    }
    best = dpp_reduce_max_u64(best);
    if ((t & 63) == 63) atomicMax(&slot[s & 3], best);
    if (t == 0) slot[(s + 2) & 3] = 0;  // prepare slot for epoch s+2
    __syncthreads();
    const ull kk = slot[s & 3];
    const int widx = 4095 - (int)(kk & 0xFFFFFFFFu);
    lx = plds[3 * widx + 0];
    ly = plds[3 * widx + 1];
    lz = plds[3 * widx + 2];
    if (t == 0) {
      fps_idx[b * NS + s] = widx;
      out_pos[((size_t)b * NS + s) * 3 + 0] = lx;
      out_pos[((size_t)b * NS + s) * 3 + 1] = ly;
      out_pos[((size_t)b * NS + s) * 3 + 2] = lz;
    }
  }
}

// ---------------------------------------------------------------------------
// KNN: block = 32 samples x 8 chunks (256 threads), batch pos in LDS.
// ---------------------------------------------------------------------------
__global__ __launch_bounds__(256) void knn_kernel(const float* __restrict__ pos,
                                                  const int* __restrict__ fps_idx,
                                                  int* __restrict__ knn_idx) {
  __shared__ ull sbuf[NPTS * 3 / 2];  // 48KB, floats during scan, keys after
  float* plds = (float*)sbuf;
  const int b = blockIdx.y;
  const int t = threadIdx.x;

  const float* p = pos + (size_t)b * NPTS * 3;
  for (int i = t; i < NPTS * 3; i += 256) plds[i] = p[i];
  __syncthreads();

  const int samp = blockIdx.x * 32 + (t >> 3);
  const int chunk = t & 7;
  const int sidx = fps_idx[b * NS + samp];
  const float sx = plds[sidx * 3 + 0];
  const float sy = plds[sidx * 3 + 1];
  const float sz = plds[sidx * 3 + 2];

  ull keys[16];
#pragma unroll
  for (int k = 0; k < 16; ++k) keys[k] = 0xFFFFFFFF00000000ull | (unsigned)k;
  ull worst = 0xFFFFFFFF0000000Full;

  for (int j = 0; j < 512; ++j) {
    const int i = j * 8 + chunk;
    const float dx = plds[i * 3 + 0] - sx;
    const float dy = plds[i * 3 + 1] - sy;
    const float dz = plds[i * 3 + 2] - sz;
    const float d = dx * dx + dy * dy + dz * dz;
    const ull key = ((ull)__float_as_uint(d) << 32) | (unsigned)i;
    if (key < worst) {
#pragma unroll
      for (int k = 0; k < 16; ++k) keys[k] = (keys[k] == worst) ? key : keys[k];
      ull w = keys[0];
#pragma unroll
      for (int k = 1; k < 16; ++k) w = umax64(w, keys[k]);
      worst = w;
    }
  }
  __syncthreads();
#pragma unroll
  for (int k = 0; k < 16; ++k) sbuf[t * 16 + k] = keys[k];
  __syncthreads();

  if (t < 32) {
    ull best[16];
#pragma unroll
    for (int k = 0; k < 16; ++k) best[k] = 0xFFFFFFFF00000000ull | (unsigned)(64 + k);
    ull w = 0xFFFFFFFF00000000ull | (unsigned)(64 + 15);
    for (int c = 0; c < 8; ++c) {
#pragma unroll
      for (int k = 0; k < 16; ++k) {
        const ull key = sbuf[(t * 8 + c) * 16 + k];
        if (key < w) {
#pragma unroll
          for (int q = 0; q < 16; ++q) best[q] = (best[q] == w) ? key : best[q];
          ull nw = best[0];
#pragma unroll
          for (int q = 1; q < 16; ++q) nw = umax64(nw, best[q]);
          w = nw;
        }
      }
    }
    const int sampg = blockIdx.x * 32 + t;
#pragma unroll
    for (int k = 0; k < 16; ++k)
      knn_idx[((size_t)b * NS + sampg) * NK + k] = (int)(best[k] & 0xFFFFFFFFu);
  }
}

// ---------------------------------------------------------------------------
// Stats: per-channel sum / sumsq of h = x W^T + b without materializing h.
// ---------------------------------------------------------------------------
__global__ __launch_bounds__(128) void stats_kernel(const float* __restrict__ x,
                                                    const float* __restrict__ W,
                                                    const float* __restrict__ bias,
                                                    float* __restrict__ partial) {
  const int blk = blockIdx.x;
  const int c = threadIdx.x;
  __shared__ float xl[128 * 64];

  const float4* Wv = (const float4*)(W + c * NF);
  float4 w[16];
#pragma unroll
  for (int q = 0; q < 16; ++q) w[q] = Wv[q];
  const float bb = bias[c];

  const float4* src = (const float4*)(x + (size_t)blk * 128 * NF);
  float4* dst = (float4*)xl;
  for (int i = c; i < 128 * NF / 4; i += 128) dst[i] = src[i];
  __syncthreads();

  float s = 0.f, s2 = 0.f;
  for (int r = 0; r < 128; ++r) {
    const float4* xr = (const float4*)(xl + r * NF);
    float h = bb;
#pragma unroll
    for (int q = 0; q < 16; ++q) {
      const float4 xv = xr[q];
      h = fmaf(xv.x, w[q].x, h);
      h = fmaf(xv.y, w[q].y, h);
      h = fmaf(xv.z, w[q].z, h);
      h = fmaf(xv.w, w[q].w, h);
    }
    s += h;
    s2 = fmaf(h, h, s2);
  }
  partial[blk * 256 + c] = s;
  partial[blk * 256 + 128 + c] = s2;
}

__global__ __launch_bounds__(256) void stats_reduce_kernel(
    const float* __restrict__ partial, const float* __restrict__ gamma,
    const float* __restrict__ beta, float* __restrict__ ab) {
  const int t = threadIdx.x;
  const int c = t & 127;
  const int h = t >> 7;
  __shared__ double sred[256], s2red[256];
  double s = 0.0, s2 = 0.0;
#pragma unroll 4
  for (int blk = h * 128; blk < h * 128 + 128; ++blk) {
    s += (double)partial[blk * 256 + c];
    s2 += (double)partial[blk * 256 + 128 + c];
  }
  sred[t] = s;
  s2red[t] = s2;
  __syncthreads();
  if (t < 128) {
    s = sred[t] + sred[t + 128];
    s2 = s2red[t] + s2red[t + 128];
    const double n = 32768.0;
    const double mean = s / n;
    const double var = s2 / n - mean * mean;
    const float inv = (float)(1.0 / sqrt(var + 1e-5));
    const float scale = gamma[t] * inv;
    const float shift = beta[t] - (float)mean * scale;
    ab[t] = scale;
    ab[128 + t] = shift;
  }
}

// ---------------------------------------------------------------------------
// Gather-max: block = 8 samples of one batch, 256 threads (channel c = t&127,
// half = t>>7 handles 4 samples). All 128 neighbor rows staged once (1 barrier),
// then barrier-free compute on all 4 SIMDs.
// ---------------------------------------------------------------------------
__global__ __launch_bounds__(256) void gather_kernel(const float* __restrict__ x,
                                                     const float* __restrict__ W,
                                                     const float* __restrict__ bias,
                                                     const float* __restrict__ ab,
                                                     const int* __restrict__ knn_idx,
                                                     float* __restrict__ out) {
  const int b = blockIdx.y;
  const int s0 = blockIdx.x * 8;
  const int t = threadIdx.x;
  const int c = t & 127;
  const int half = t >> 7;

  const float4* Wv = (const float4*)(W + c * NF);
  float4 w[16];
#pragma unroll
  for (int q = 0; q < 16; ++q) w[q] = Wv[q];
  const float bb = bias[c];
  const float scale = ab[c];
  const float shift = ab[128 + c];

  __shared__ float xl[128 * NF];  // 32KB: row r = (sample s0+(r>>4), neighbor r&15)
  {
    const int r = c;               // row 0..127
    const int q0 = half * 8;       // each half loads 8 float4 of the row
    const int idx = knn_idx[((size_t)b * NS + s0 + (r >> 4)) * NK + (r & 15)];
    const float4* srow = (const float4*)(x + (size_t)b * NPTS * NF + (size_t)idx * NF) + q0;
    float4* drow = (float4*)(xl + r * NF) + q0;
#pragma unroll
    for (int q = 0; q < 8; ++q) drow[q] = srow[q];
  }
  __syncthreads();

  for (int ss = half * 4; ss < half * 4 + 4; ++ss) {
    float m = 0.0f;  // relu >= 0
#pragma unroll
    for (int k = 0; k < NK; ++k) {
      const float4* xr = (const float4*)(xl + (ss * 16 + k) * NF);
      float h = bb;
#pragma unroll
      for (int q = 0; q < 16; ++q) {
        const float4 xv = xr[q];
        h = fmaf(xv.x, w[q].x, h);
        h = fmaf(xv.y, w[q].y, h);
        h = fmaf(xv.z, w[q].z, h);
        h = fmaf(xv.w, w[q].w, h);
      }
      h = fmaf(h, scale, shift);
      h = h > 0.f ? h : 0.f;
      m = m > h ? m : h;
    }
    out[((size_t)b * NS + s0 + ss) * NO + c] = m;
  }
}

// ---------------------------------------------------------------------------
extern "C" void kernel_launch(void* const* d_in, const int* in_sizes, int n_in,
                              void* d_out, int out_size, void* d_ws, size_t ws_size,
                              hipStream_t stream) {
  const float* x     = (const float*)d_in[0];  // [8,4096,64]
  const float* pos   = (const float*)d_in[1];  // [8,4096,3]
  const float* W     = (const float*)d_in[2];  // [128,64]
  const float* bias  = (const float*)d_in[3];  // [128]
  const float* gamma = (const float*)d_in[4];  // [128]
  const float* beta  = (const float*)d_in[5];  // [128]

  float* out_knn = (float*)d_out;                       // [8,1024,128]
  float* out_pos = out_knn + (size_t)NBATCH * NS * NO;  // [8,1024,3]

  char* ws = (char*)d_ws;
  int* fps_idx   = (int*)(ws);                 // 8*1024 ints      (32KB)
  int* knn_idx   = (int*)(ws + (32 << 10));    // 8*1024*16 ints   (512KB)
  float* partial = (float*)(ws + (544 << 10)); // 256*256 floats   (256KB)
  float* ab      = (float*)(ws + (800 << 10)); // 256 floats

  fps_kernel<<<NBATCH, FT, 0, stream>>>(pos, fps_idx, out_pos);
  stats_kernel<<<256, 128, 0, stream>>>(x, W, bias, partial);
  stats_reduce_kernel<<<1, 256, 0, stream>>>(partial, gamma, beta, ab);
  knn_kernel<<<dim3(32, NBATCH), 256, 0, stream>>>(pos, fps_idx, knn_idx);
  gather_kernel<<<dim3(NS / 8, NBATCH), 256, 0, stream>>>(x, W, bias, ab, knn_idx,
                                                          out_knn);
}

// Round 4
// 1139.885 us; speedup vs baseline: 1.2131x; 1.0304x over previous
//
#include <hip/hip_runtime.h>
#include <stdint.h>

typedef unsigned long long ull;
typedef float f32x2 __attribute__((ext_vector_type(2)));

#define NBATCH 8
#define NPTS   4096
#define NS     1024
#define NK     16
#define NF     64
#define NO     128

#define FT  512  // fps threads (8 waves, 2 per SIMD)
#define PPT 8    // points per thread (4096/512)

static __device__ __forceinline__ ull umax64(ull a, ull b) { return a > b ? a : b; }

// DPP max-reduce of a 64-bit key across the 64-lane wave; result in lane 63.
static __device__ __forceinline__ ull dpp_reduce_max_u64(ull v) {
#define DPP_STEP(ctrl)                                                        \
  {                                                                           \
    const unsigned lo = (unsigned)v;                                          \
    const unsigned hi = (unsigned)(v >> 32);                                  \
    const unsigned lo2 =                                                      \
        (unsigned)__builtin_amdgcn_update_dpp(0, (int)lo, ctrl, 0xf, 0xf, true); \
    const unsigned hi2 =                                                      \
        (unsigned)__builtin_amdgcn_update_dpp(0, (int)hi, ctrl, 0xf, 0xf, true); \
    const ull o = ((ull)hi2 << 32) | lo2;                                     \
    v = v > o ? v : o;                                                        \
  }
  DPP_STEP(0x111)  // row_shr:1
  DPP_STEP(0x112)  // row_shr:2
  DPP_STEP(0x114)  // row_shr:4
  DPP_STEP(0x118)  // row_shr:8
  DPP_STEP(0x142)  // row_bcast15
  DPP_STEP(0x143)  // row_bcast31 -> lane 63 has wave max
#undef DPP_STEP
  return v;
}

// ---------------------------------------------------------------------------
// FPS: one block per batch, 512 threads, 8 points/thread. Packed-f32 distance
// math (IEEE f32, contract off => bit-exact vs numpy's ((dx^2+dy^2)+dz^2)).
// NO global stores inside the step loop (a global store would force the
// compiler's pre-barrier s_waitcnt vmcnt(0) to drain HBM every step): winners
// buffered in LDS, dumped once at the end.
// ---------------------------------------------------------------------------
__global__ __launch_bounds__(FT) void fps_kernel(const float* __restrict__ pos,
                                                 int* __restrict__ fps_idx,
                                                 float* __restrict__ out_pos) {
#pragma clang fp contract(off)
  const int b = blockIdx.x;
  const int t = threadIdx.x;
  __shared__ float plds[NPTS * 3];
  __shared__ __align__(16) ull wkeys[2][8];
  __shared__ int widx_lds[NS];

  const float* p = pos + (size_t)b * NPTS * 3;
  {
    const float4* src = (const float4*)p;
    float4* dst = (float4*)plds;
    for (int i = t; i < NPTS * 3 / 4; i += FT) dst[i] = src[i];
  }
  if (t == 0) widx_lds[0] = 0;
  __syncthreads();

  f32x2 px2[PPT / 2], py2[PPT / 2], pz2[PPT / 2], md2[PPT / 2];
  unsigned lowk[PPT];
#pragma unroll
  for (int jp = 0; jp < PPT / 2; ++jp) {
    const int i0 = t + FT * (2 * jp);
    const int i1 = i0 + FT;
    px2[jp] = (f32x2){plds[3 * i0 + 0], plds[3 * i1 + 0]};
    py2[jp] = (f32x2){plds[3 * i0 + 1], plds[3 * i1 + 1]};
    pz2[jp] = (f32x2){plds[3 * i0 + 2], plds[3 * i1 + 2]};
    md2[jp] = (f32x2){1e10f, 1e10f};
    lowk[2 * jp] = 4095 - i0;
    lowk[2 * jp + 1] = 4095 - i1;
  }

  float lx = plds[0], ly = plds[1], lz = plds[2];

  for (int s = 1; s < NS; ++s) {
    const f32x2 lxv = (f32x2){lx, lx};
    const f32x2 lyv = (f32x2){ly, ly};
    const f32x2 lzv = (f32x2){lz, lz};
    ull best = 0;
#pragma unroll
    for (int jp = 0; jp < PPT / 2; ++jp) {
      const f32x2 dx = px2[jp] - lxv;  // v_pk_add(neg) — IEEE f32
      const f32x2 dy = py2[jp] - lyv;
      const f32x2 dz = pz2[jp] - lzv;
      const f32x2 xx = dx * dx;        // v_pk_mul
      const f32x2 yy = dy * dy;
      const f32x2 zz = dz * dz;
      const f32x2 sxy = xx + yy;
      const f32x2 d = sxy + zz;        // ((dx^2+dy^2)+dz^2), numpy order
      const float m0 = fminf(md2[jp].x, d.x);
      const float m1 = fminf(md2[jp].y, d.y);
      md2[jp].x = m0;
      md2[jp].y = m1;
      const ull k0 = ((ull)__float_as_uint(m0) << 32) | lowk[2 * jp];
      const ull k1 = ((ull)__float_as_uint(m1) << 32) | lowk[2 * jp + 1];
      best = umax64(best, umax64(k0, k1));
    }
    best = dpp_reduce_max_u64(best);
    if ((t & 63) == 63) wkeys[s & 1][t >> 6] = best;
    __syncthreads();
    // merge the 8 wave keys (tree of umax64; LDS reads are same-addr broadcast)
    const ull* wk = wkeys[s & 1];
    const ull m01 = umax64(wk[0], wk[1]);
    const ull m23 = umax64(wk[2], wk[3]);
    const ull m45 = umax64(wk[4], wk[5]);
    const ull m67 = umax64(wk[6], wk[7]);
    const ull kk = umax64(umax64(m01, m23), umax64(m45, m67));
    const int widx = 4095 - (int)(kk & 0xFFFFFFFFu);
    lx = plds[3 * widx + 0];
    ly = plds[3 * widx + 1];
    lz = plds[3 * widx + 2];
    if (t == 0) widx_lds[s] = widx;
    // wkeys double-buffered: the next write to this slot (step s+2) is
    // separated from this read by the barrier of step s+1 — race-free.
  }

  __syncthreads();
  for (int i = t; i < NS; i += FT) {
    const int wi = widx_lds[i];
    fps_idx[b * NS + i] = wi;
    out_pos[((size_t)b * NS + i) * 3 + 0] = plds[3 * wi + 0];
    out_pos[((size_t)b * NS + i) * 3 + 1] = plds[3 * wi + 1];
    out_pos[((size_t)b * NS + i) * 3 + 2] = plds[3 * wi + 2];
  }
}

// ---------------------------------------------------------------------------
// KNN: block = 32 samples x 8 chunks (256 threads), batch pos in LDS.
// ---------------------------------------------------------------------------
__global__ __launch_bounds__(256) void knn_kernel(const float* __restrict__ pos,
                                                  const int* __restrict__ fps_idx,
                                                  int* __restrict__ knn_idx) {
  __shared__ ull sbuf[NPTS * 3 / 2];  // 48KB, floats during scan, keys after
  float* plds = (float*)sbuf;
  const int b = blockIdx.y;
  const int t = threadIdx.x;

  const float* p = pos + (size_t)b * NPTS * 3;
  for (int i = t; i < NPTS * 3; i += 256) plds[i] = p[i];
  __syncthreads();

  const int samp = blockIdx.x * 32 + (t >> 3);
  const int chunk = t & 7;
  const int sidx = fps_idx[b * NS + samp];
  const float sx = plds[sidx * 3 + 0];
  const float sy = plds[sidx * 3 + 1];
  const float sz = plds[sidx * 3 + 2];

  ull keys[16];
#pragma unroll
  for (int k = 0; k < 16; ++k) keys[k] = 0xFFFFFFFF00000000ull | (unsigned)k;
  ull worst = 0xFFFFFFFF0000000Full;

  for (int j = 0; j < 512; ++j) {
    const int i = j * 8 + chunk;
    const float dx = plds[i * 3 + 0] - sx;
    const float dy = plds[i * 3 + 1] - sy;
    const float dz = plds[i * 3 + 2] - sz;
    const float d = dx * dx + dy * dy + dz * dz;
    const ull key = ((ull)__float_as_uint(d) << 32) | (unsigned)i;
    if (key < worst) {
#pragma unroll
      for (int k = 0; k < 16; ++k) keys[k] = (keys[k] == worst) ? key : keys[k];
      ull w = keys[0];
#pragma unroll
      for (int k = 1; k < 16; ++k) w = umax64(w, keys[k]);
      worst = w;
    }
  }
  __syncthreads();
#pragma unroll
  for (int k = 0; k < 16; ++k) sbuf[t * 16 + k] = keys[k];
  __syncthreads();

  if (t < 32) {
    ull best[16];
#pragma unroll
    for (int k = 0; k < 16; ++k) best[k] = 0xFFFFFFFF00000000ull | (unsigned)(64 + k);
    ull w = 0xFFFFFFFF00000000ull | (unsigned)(64 + 15);
    for (int c = 0; c < 8; ++c) {
#pragma unroll
      for (int k = 0; k < 16; ++k) {
        const ull key = sbuf[(t * 8 + c) * 16 + k];
        if (key < w) {
#pragma unroll
          for (int q = 0; q < 16; ++q) best[q] = (best[q] == w) ? key : best[q];
          ull nw = best[0];
#pragma unroll
          for (int q = 1; q < 16; ++q) nw = umax64(nw, best[q]);
          w = nw;
        }
      }
    }
    const int sampg = blockIdx.x * 32 + t;
#pragma unroll
    for (int k = 0; k < 16; ++k)
      knn_idx[((size_t)b * NS + sampg) * NK + k] = (int)(best[k] & 0xFFFFFFFFu);
  }
}

// ---------------------------------------------------------------------------
// Stats: per-channel sum / sumsq of h = x W^T + b without materializing h.
// ---------------------------------------------------------------------------
__global__ __launch_bounds__(128) void stats_kernel(const float* __restrict__ x,
                                                    const float* __restrict__ W,
                                                    const float* __restrict__ bias,
                                                    float* __restrict__ partial) {
  const int blk = blockIdx.x;
  const int c = threadIdx.x;
  __shared__ float xl[128 * 64];

  const float4* Wv = (const float4*)(W + c * NF);
  float4 w[16];
#pragma unroll
  for (int q = 0; q < 16; ++q) w[q] = Wv[q];
  const float bb = bias[c];

  const float4* src = (const float4*)(x + (size_t)blk * 128 * NF);
  float4* dst = (float4*)xl;
  for (int i = c; i < 128 * NF / 4; i += 128) dst[i] = src[i];
  __syncthreads();

  float s = 0.f, s2 = 0.f;
  for (int r = 0; r < 128; ++r) {
    const float4* xr = (const float4*)(xl + r * NF);
    float h = bb;
#pragma unroll
    for (int q = 0; q < 16; ++q) {
      const float4 xv = xr[q];
      h = fmaf(xv.x, w[q].x, h);
      h = fmaf(xv.y, w[q].y, h);
      h = fmaf(xv.z, w[q].z, h);
      h = fmaf(xv.w, w[q].w, h);
    }
    s += h;
    s2 = fmaf(h, h, s2);
  }
  partial[blk * 256 + c] = s;
  partial[blk * 256 + 128 + c] = s2;
}

__global__ __launch_bounds__(256) void stats_reduce_kernel(
    const float* __restrict__ partial, const float* __restrict__ gamma,
    const float* __restrict__ beta, float* __restrict__ ab) {
  const int t = threadIdx.x;
  const int c = t & 127;
  const int h = t >> 7;
  __shared__ double sred[256], s2red[256];
  double s = 0.0, s2 = 0.0;
#pragma unroll 4
  for (int blk = h * 128; blk < h * 128 + 128; ++blk) {
    s += (double)partial[blk * 256 + c];
    s2 += (double)partial[blk * 256 + 128 + c];
  }
  sred[t] = s;
  s2red[t] = s2;
  __syncthreads();
  if (t < 128) {
    s = sred[t] + sred[t + 128];
    s2 = s2red[t] + s2red[t + 128];
    const double n = 32768.0;
    const double mean = s / n;
    const double var = s2 / n - mean * mean;
    const float inv = (float)(1.0 / sqrt(var + 1e-5));
    const float scale = gamma[t] * inv;
    const float shift = beta[t] - (float)mean * scale;
    ab[t] = scale;
    ab[128 + t] = shift;
  }
}

// ---------------------------------------------------------------------------
// Gather-max: block = 8 samples of one batch, 256 threads (channel c = t&127,
// half = t>>7 handles 4 samples).
// ---------------------------------------------------------------------------
__global__ __launch_bounds__(256) void gather_kernel(const float* __restrict__ x,
                                                     const float* __restrict__ W,
                                                     const float* __restrict__ bias,
                                                     const float* __restrict__ ab,
                                                     const int* __restrict__ knn_idx,
                                                     float* __restrict__ out) {
  const int b = blockIdx.y;
  const int s0 = blockIdx.x * 8;
  const int t = threadIdx.x;
  const int c = t & 127;
  const int half = t >> 7;

  const float4* Wv = (const float4*)(W + c * NF);
  float4 w[16];
#pragma unroll
  for (int q = 0; q < 16; ++q) w[q] = Wv[q];
  const float bb = bias[c];
  const float scale = ab[c];
  const float shift = ab[128 + c];

  __shared__ float xl[128 * NF];  // 32KB: row r = (sample s0+(r>>4), neighbor r&15)
  {
    const int r = c;
    const int q0 = half * 8;
    const int idx = knn_idx[((size_t)b * NS + s0 + (r >> 4)) * NK + (r & 15)];
    const float4* srow = (const float4*)(x + (size_t)b * NPTS * NF + (size_t)idx * NF) + q0;
    float4* drow = (float4*)(xl + r * NF) + q0;
#pragma unroll
    for (int q = 0; q < 8; ++q) drow[q] = srow[q];
  }
  __syncthreads();

  for (int ss = half * 4; ss < half * 4 + 4; ++ss) {
    float m = 0.0f;  // relu >= 0
#pragma unroll
    for (int k = 0; k < NK; ++k) {
      const float4* xr = (const float4*)(xl + (ss * 16 + k) * NF);
      float h = bb;
#pragma unroll
      for (int q = 0; q < 16; ++q) {
        const float4 xv = xr[q];
        h = fmaf(xv.x, w[q].x, h);
        h = fmaf(xv.y, w[q].y, h);
        h = fmaf(xv.z, w[q].z, h);
        h = fmaf(xv.w, w[q].w, h);
      }
      h = fmaf(h, scale, shift);
      h = h > 0.f ? h : 0.f;
      m = m > h ? m : h;
    }
    out[((size_t)b * NS + s0 + ss) * NO + c] = m;
  }
}

// ---------------------------------------------------------------------------
extern "C" void kernel_launch(void* const* d_in, const int* in_sizes, int n_in,
                              void* d_out, int out_size, void* d_ws, size_t ws_size,
                              hipStream_t stream) {
  const float* x     = (const float*)d_in[0];  // [8,4096,64]
  const float* pos   = (const float*)d_in[1];  // [8,4096,3]
  const float* W     = (const float*)d_in[2];  // [128,64]
  const float* bias  = (const float*)d_in[3];  // [128]
  const float* gamma = (const float*)d_in[4];  // [128]
  const float* beta  = (const float*)d_in[5];  // [128]

  float* out_knn = (float*)d_out;                       // [8,1024,128]
  float* out_pos = out_knn + (size_t)NBATCH * NS * NO;  // [8,1024,3]

  char* ws = (char*)d_ws;
  int* fps_idx   = (int*)(ws);                 // 8*1024 ints      (32KB)
  int* knn_idx   = (int*)(ws + (32 << 10));    // 8*1024*16 ints   (512KB)
  float* partial = (float*)(ws + (544 << 10)); // 256*256 floats   (256KB)
  float* ab      = (float*)(ws + (800 << 10)); // 256 floats

  fps_kernel<<<NBATCH, FT, 0, stream>>>(pos, fps_idx, out_pos);
  stats_kernel<<<256, 128, 0, stream>>>(x, W, bias, partial);
  stats_reduce_kernel<<<1, 256, 0, stream>>>(partial, gamma, beta, ab);
  knn_kernel<<<dim3(32, NBATCH), 256, 0, stream>>>(pos, fps_idx, knn_idx);
  gather_kernel<<<dim3(NS / 8, NBATCH), 256, 0, stream>>>(x, W, bias, ab, knn_idx,
                                                          out_knn);
}